// Round 1
// baseline (487.883 us; speedup 1.0000x reference)
//
#include <hip/hip_runtime.h>
#include <math.h>

// Problem constants
#define N_  8
#define C_  256
#define G_  8
#define CG_ 32
#define K_  9
#define H_  64
#define W_  64
#define L_  (H_*W_)      // 4096
#define OM_ 216          // G*K*3

// ---------------------------------------------------------------------------
// Kernel 1: depthwise 3x3 conv, SAME padding, NCHW -> NCHW (om_in)
// grid (H/4, C, N), block 256 (4 rows of 64)
// ---------------------------------------------------------------------------
__global__ __launch_bounds__(256) void dw_kernel(const float* __restrict__ x,
                                                 const float* __restrict__ w,
                                                 const float* __restrict__ b,
                                                 float* __restrict__ om_in) {
    const int n = blockIdx.z;
    const int c = blockIdx.y;
    const int tid = threadIdx.x;
    const int y = blockIdx.x * 4 + (tid >> 6);
    const int xx = tid & 63;
    const float* xp = x + ((size_t)(n * C_ + c)) * L_;
    float wv[9];
#pragma unroll
    for (int i = 0; i < 9; i++) wv[i] = w[c * 9 + i];
    float acc = b[c];
#pragma unroll
    for (int dy = -1; dy <= 1; dy++) {
        int yy = y + dy;
        if (yy < 0 || yy >= H_) continue;
#pragma unroll
        for (int dx = -1; dx <= 1; dx++) {
            int x2 = xx + dx;
            if (x2 < 0 || x2 >= W_) continue;
            acc += wv[(dy + 1) * 3 + (dx + 1)] * xp[yy * W_ + x2];
        }
    }
    om_in[((size_t)(n * C_ + c)) * L_ + y * W_ + xx] = acc;
}

// ---------------------------------------------------------------------------
// Kernel 2: GEMM with K-major A (A[k][m], stride L_), W row-major (NTOT x 256)
// D[m][q] = sum_k A[k][m]*W[q][k] + bias[q];  D per batch is (L_ x NTOT)
// grid (L_/64, ceil(NTOT/64), N_), block 256. 64x64 tile, BK=16, 4x4 microtile
// tx (=tid&15) indexes q-frag, ty (=tid>>4) indexes m-frag.
// ---------------------------------------------------------------------------
template <int NTOT>
__global__ __launch_bounds__(256) void gemm_akm(const float* __restrict__ A,
                                                const float* __restrict__ Wm,
                                                const float* __restrict__ bias,
                                                float* __restrict__ D) {
    __shared__ float As[16][64];   // [k][m]
    __shared__ float Ws[16][68];   // [k][q], padded
    const int n = blockIdx.z;
    const int m0 = blockIdx.x * 64;
    const int q0 = blockIdx.y * 64;
    const int tid = threadIdx.x;
    const int tx = tid & 15;   // q-frag
    const int ty = tid >> 4;   // m-frag
    const float* Ab = A + (size_t)n * C_ * L_ + m0;
    float acc[4][4] = {{0.f}};   // [m_i][q_j]

    for (int k0 = 0; k0 < C_; k0 += 16) {
        {   // A tile: 16 k-rows x 64 m-cols; each row contiguous in m
            int r = tid >> 4, c4 = (tid & 15) * 4;
            float4 av = *(const float4*)(Ab + (size_t)(k0 + r) * L_ + c4);
            *(float4*)&As[r][c4] = av;
        }
        {   // W tile: rows q, 16 contiguous k each; store transposed [k][q]
            int qi = tid >> 2, k4 = (tid & 3) * 4;
            float4 wv = make_float4(0.f, 0.f, 0.f, 0.f);
            if (NTOT == 256 || (q0 + qi) < NTOT)
                wv = *(const float4*)(Wm + (size_t)(q0 + qi) * C_ + k0 + k4);
            Ws[k4 + 0][qi] = wv.x; Ws[k4 + 1][qi] = wv.y;
            Ws[k4 + 2][qi] = wv.z; Ws[k4 + 3][qi] = wv.w;
        }
        __syncthreads();
#pragma unroll
        for (int k = 0; k < 16; k++) {
            float4 a4 = *(const float4*)&As[k][ty * 4];
            float4 w4 = *(const float4*)&Ws[k][tx * 4];
            float am[4] = {a4.x, a4.y, a4.z, a4.w};
            float wq[4] = {w4.x, w4.y, w4.z, w4.w};
#pragma unroll
            for (int i = 0; i < 4; i++)
#pragma unroll
                for (int j = 0; j < 4; j++) acc[i][j] += am[i] * wq[j];
        }
        __syncthreads();
    }

    float* Dp = D + (size_t)n * L_ * NTOT;
    const int q = q0 + tx * 4;
    if (NTOT == 256 || q < NTOT) {
        float4 bv = *(const float4*)(bias + q);
#pragma unroll
        for (int i = 0; i < 4; i++) {
            int m = m0 + ty * 4 + i;
            float4 v = make_float4(acc[i][0] + bv.x, acc[i][1] + bv.y,
                                   acc[i][2] + bv.z, acc[i][3] + bv.w);
            *(float4*)(Dp + (size_t)m * NTOT + q) = v;
        }
    }
}

// ---------------------------------------------------------------------------
// Kernel 3: deformable bilinear sampling + mask accumulation
// grid (L_, N_), block 256: thread = (g = tid>>5, cg = tid&31)
// value: (n, L, G, CG) fp32;  om: (n, L, 216);  interm: (n, L, C)
// ---------------------------------------------------------------------------
__global__ __launch_bounds__(256) void sample_kernel(const float* __restrict__ value,
                                                     const float* __restrict__ om,
                                                     float* __restrict__ interm) {
    const int n = blockIdx.y;
    const int l = blockIdx.x;
    const int y = l >> 6, x = l & 63;
    const int tid = threadIdx.x;
    const int g = tid >> 5;

    __shared__ float sOm[OM_];
    if (tid < OM_) sOm[tid] = om[((size_t)n * L_ + l) * OM_ + tid];
    __syncthreads();

    const float* vb = value + (size_t)n * L_ * C_ + tid;  // tid == g*32+cg
    float acc = 0.f;
#pragma unroll
    for (int k = 0; k < K_; k++) {
        float offy = sOm[g * 27 + 2 * k];
        float offx = sOm[g * 27 + 2 * k + 1];
        float mk   = sOm[g * 27 + 18 + k];
        float py = (float)y + (float)(k / 3 - 1) + offy;
        float px = (float)x + (float)(k % 3 - 1) + offx;
        float fy = floorf(py), fx = floorf(px);
        float ty = py - fy, tx = px - fx;
        int y0 = (int)fy, x0 = (int)fx;
        int y1 = y0 + 1, x1 = x0 + 1;
        float w00 = (1.f - ty) * (1.f - tx), w01 = (1.f - ty) * tx;
        float w10 = ty * (1.f - tx),         w11 = ty * tx;
        bool vy0 = (y0 >= 0) & (y0 < H_), vy1 = (y1 >= 0) & (y1 < H_);
        bool vx0 = (x0 >= 0) & (x0 < W_), vx1 = (x1 >= 0) & (x1 < W_);
        float s = 0.f;
        if (vy0 & vx0) s += w00 * vb[(size_t)(y0 * W_ + x0) * C_];
        if (vy0 & vx1) s += w01 * vb[(size_t)(y0 * W_ + x1) * C_];
        if (vy1 & vx0) s += w10 * vb[(size_t)(y1 * W_ + x0) * C_];
        if (vy1 & vx1) s += w11 * vb[(size_t)(y1 * W_ + x1) * C_];
        acc += mk * s;
    }
    interm[((size_t)n * L_ + l) * C_ + tid] = acc;
}

// ---------------------------------------------------------------------------
// Kernel 4: final GEMM, A row-major (L_ x C_), output TRANSPOSED: (C_ x L_)
// out[q][m] = sum_k A[m][k] * W[q][k]
// grid (L_/64, C_/64, N_), block 256. tx (=tid&15) -> m-frag, ty -> q-frag
// so the store along m is lane-contiguous (out rows are contiguous in l).
// ---------------------------------------------------------------------------
__global__ __launch_bounds__(256) void gemm_final(const float* __restrict__ A,
                                                  const float* __restrict__ Wm,
                                                  float* __restrict__ Dt) {
    __shared__ float As[16][68];   // [k][m]
    __shared__ float Ws[16][68];   // [k][q]
    const int n = blockIdx.z;
    const int m0 = blockIdx.x * 64;
    const int q0 = blockIdx.y * 64;
    const int tid = threadIdx.x;
    const int tx = tid & 15;   // m-frag
    const int ty = tid >> 4;   // q-frag
    const float* Ab = A + (size_t)n * L_ * C_;
    float acc[4][4] = {{0.f}};   // [m_i][q_j]

    for (int k0 = 0; k0 < C_; k0 += 16) {
        {   // A tile (row-major rows) -> transposed store As[k][m]
            int mi = tid >> 2, k4 = (tid & 3) * 4;
            float4 av = *(const float4*)(Ab + (size_t)(m0 + mi) * C_ + k0 + k4);
            As[k4 + 0][mi] = av.x; As[k4 + 1][mi] = av.y;
            As[k4 + 2][mi] = av.z; As[k4 + 3][mi] = av.w;
        }
        {   // W tile -> transposed store Ws[k][q]
            int qi = tid >> 2, k4 = (tid & 3) * 4;
            float4 wv = *(const float4*)(Wm + (size_t)(q0 + qi) * C_ + k0 + k4);
            Ws[k4 + 0][qi] = wv.x; Ws[k4 + 1][qi] = wv.y;
            Ws[k4 + 2][qi] = wv.z; Ws[k4 + 3][qi] = wv.w;
        }
        __syncthreads();
#pragma unroll
        for (int k = 0; k < 16; k++) {
            float4 a4 = *(const float4*)&As[k][tx * 4];
            float4 w4 = *(const float4*)&Ws[k][ty * 4];
            float am[4] = {a4.x, a4.y, a4.z, a4.w};
            float wq[4] = {w4.x, w4.y, w4.z, w4.w};
#pragma unroll
            for (int i = 0; i < 4; i++)
#pragma unroll
                for (int j = 0; j < 4; j++) acc[i][j] += am[i] * wq[j];
        }
        __syncthreads();
    }

    float* Db = Dt + (size_t)n * C_ * L_;
#pragma unroll
    for (int j = 0; j < 4; j++) {
        int q = q0 + ty * 4 + j;
        float4 v = make_float4(acc[0][j], acc[1][j], acc[2][j], acc[3][j]);
        *(float4*)(Db + (size_t)q * L_ + m0 + tx * 4) = v;
    }
}

// ---------------------------------------------------------------------------
// Launch. Workspace layout (needs 95,420,416 B):
//   [0, 33554432)            value  (N,L,C)  fp32
//   [33554432, 61865984)     om     (N,L,216) fp32
//   [61865984, 95420416)     buf    (N,L,C)  fp32 — om_in, then reused as interm
// ---------------------------------------------------------------------------
extern "C" void kernel_launch(void* const* d_in, const int* in_sizes, int n_in,
                              void* d_out, int out_size, void* d_ws, size_t ws_size,
                              hipStream_t stream) {
    const float* x    = (const float*)d_in[0];
    const float* dw_w = (const float*)d_in[1];
    const float* dw_b = (const float*)d_in[2];
    const float* om_w = (const float*)d_in[3];
    const float* om_b = (const float*)d_in[4];
    const float* vp_w = (const float*)d_in[5];
    const float* vp_b = (const float*)d_in[6];
    const float* op_w = (const float*)d_in[7];
    float* out = (float*)d_out;

    char* ws = (char*)d_ws;
    float* value = (float*)(ws);
    float* om    = (float*)(ws + 33554432);
    float* buf   = (float*)(ws + 61865984);   // om_in then interm

    // 1) depthwise conv -> buf (om_in)
    dw_kernel<<<dim3(H_ / 4, C_, N_), 256, 0, stream>>>(x, dw_w, dw_b, buf);
    // 2) value projection: value = x^T @ vp_w^T + vp_b
    gemm_akm<256><<<dim3(L_ / 64, 4, N_), 256, 0, stream>>>(x, vp_w, vp_b, value);
    // 3) offset/mask projection: om = om_in^T @ om_w^T + om_b
    gemm_akm<216><<<dim3(L_ / 64, 4, N_), 256, 0, stream>>>(buf, om_w, om_b, om);
    // 4) deformable sampling -> buf (interm, overwrites om_in after it's consumed)
    sample_kernel<<<dim3(L_, N_), 256, 0, stream>>>(value, om, buf);
    // 5) output projection (transposed store -> NCHW out)
    gemm_final<<<dim3(L_ / 64, C_ / 64, N_), 256, 0, stream>>>(buf, op_w, out);
}

// Round 2
// 344.504 us; speedup vs baseline: 1.4162x; 1.4162x over previous
//
#include <hip/hip_runtime.h>
#include <math.h>

// Problem constants
#define N_  8
#define C_  256
#define G_  8
#define CG_ 32
#define K_  9
#define H_  64
#define W_  64
#define L_  (H_*W_)      // 4096
#define OM_ 216          // G*K*3

// ---------------------------------------------------------------------------
// Kernel 1: depthwise 3x3 conv, SAME padding, NCHW -> NCHW (om_in)
// grid (H/4, C, N), block 256 (4 rows of 64)
// ---------------------------------------------------------------------------
__global__ __launch_bounds__(256) void dw_kernel(const float* __restrict__ x,
                                                 const float* __restrict__ w,
                                                 const float* __restrict__ b,
                                                 float* __restrict__ om_in) {
    const int n = blockIdx.z;
    const int c = blockIdx.y;
    const int tid = threadIdx.x;
    const int y = blockIdx.x * 4 + (tid >> 6);
    const int xx = tid & 63;
    const float* xp = x + ((size_t)(n * C_ + c)) * L_;
    float wv[9];
#pragma unroll
    for (int i = 0; i < 9; i++) wv[i] = w[c * 9 + i];
    float acc = b[c];
#pragma unroll
    for (int dy = -1; dy <= 1; dy++) {
        int yy = y + dy;
        if (yy < 0 || yy >= H_) continue;
#pragma unroll
        for (int dx = -1; dx <= 1; dx++) {
            int x2 = xx + dx;
            if (x2 < 0 || x2 >= W_) continue;
            acc += wv[(dy + 1) * 3 + (dx + 1)] * xp[yy * W_ + x2];
        }
    }
    om_in[((size_t)(n * C_ + c)) * L_ + y * W_ + xx] = acc;
}

// ---------------------------------------------------------------------------
// Kernel 2: GEMM with K-major A (A[k][m], stride L_), W row-major (NTOT x 256)
// D[m][q] = sum_k A[k][m]*W[q][k] + bias[q];  D per batch is (L_ x NTOT)
// ---------------------------------------------------------------------------
template <int NTOT>
__global__ __launch_bounds__(256) void gemm_akm(const float* __restrict__ A,
                                                const float* __restrict__ Wm,
                                                const float* __restrict__ bias,
                                                float* __restrict__ D) {
    __shared__ float As[16][64];   // [k][m]
    __shared__ float Ws[16][68];   // [k][q], padded
    const int n = blockIdx.z;
    const int m0 = blockIdx.x * 64;
    const int q0 = blockIdx.y * 64;
    const int tid = threadIdx.x;
    const int tx = tid & 15;   // q-frag
    const int ty = tid >> 4;   // m-frag
    const float* Ab = A + (size_t)n * C_ * L_ + m0;
    float acc[4][4] = {{0.f}};   // [m_i][q_j]

    for (int k0 = 0; k0 < C_; k0 += 16) {
        {   // A tile: 16 k-rows x 64 m-cols; each row contiguous in m
            int r = tid >> 4, c4 = (tid & 15) * 4;
            float4 av = *(const float4*)(Ab + (size_t)(k0 + r) * L_ + c4);
            *(float4*)&As[r][c4] = av;
        }
        {   // W tile: rows q, 16 contiguous k each; store transposed [k][q]
            int qi = tid >> 2, k4 = (tid & 3) * 4;
            float4 wv = make_float4(0.f, 0.f, 0.f, 0.f);
            if (NTOT == 256 || (q0 + qi) < NTOT)
                wv = *(const float4*)(Wm + (size_t)(q0 + qi) * C_ + k0 + k4);
            Ws[k4 + 0][qi] = wv.x; Ws[k4 + 1][qi] = wv.y;
            Ws[k4 + 2][qi] = wv.z; Ws[k4 + 3][qi] = wv.w;
        }
        __syncthreads();
#pragma unroll
        for (int k = 0; k < 16; k++) {
            float4 a4 = *(const float4*)&As[k][ty * 4];
            float4 w4 = *(const float4*)&Ws[k][tx * 4];
            float am[4] = {a4.x, a4.y, a4.z, a4.w};
            float wq[4] = {w4.x, w4.y, w4.z, w4.w};
#pragma unroll
            for (int i = 0; i < 4; i++)
#pragma unroll
                for (int j = 0; j < 4; j++) acc[i][j] += am[i] * wq[j];
        }
        __syncthreads();
    }

    float* Dp = D + (size_t)n * L_ * NTOT;
    const int q = q0 + tx * 4;
    if (NTOT == 256 || q < NTOT) {
        float4 bv = *(const float4*)(bias + q);
#pragma unroll
        for (int i = 0; i < 4; i++) {
            int m = m0 + ty * 4 + i;
            float4 v = make_float4(acc[i][0] + bv.x, acc[i][1] + bv.y,
                                   acc[i][2] + bv.z, acc[i][3] + bv.w);
            *(float4*)(Dp + (size_t)m * NTOT + q) = v;
        }
    }
}

// ---------------------------------------------------------------------------
// Kernel 3: deformable bilinear sampling + mask accumulation (vectorized)
// grid (L_/4, N_), block 256: 4 pixels/block; per pixel 64 threads =
//   8 groups (g) x 8 threads, each thread covers 4 channels via float4.
// value: (n, L, G, CG) fp32;  om: (n, L, 216);  interm: (n, L, C)
// Branchless corners: clamp index, zero the weight (matches reference).
// ---------------------------------------------------------------------------
__global__ __launch_bounds__(256) void sample_kernel(const float* __restrict__ value,
                                                     const float* __restrict__ om,
                                                     float* __restrict__ interm) {
    const int n = blockIdx.y;
    const int l0 = blockIdx.x * 4;
    const int tid = threadIdx.x;
    const int p = tid >> 6;               // pixel within block
    const int l = l0 + p;
    const int y = l >> 6, x = l & 63;
    const int g = (tid >> 3) & 7;         // group
    const int c4 = (tid & 7) * 4;         // channel offset (float4)

    __shared__ float sOm[4 * OM_];        // 864 floats
    const float* omb = om + ((size_t)n * L_ + l0) * OM_;
#pragma unroll
    for (int i = 0; i < 4; i++) {
        int idx = tid + i * 256;
        if (idx < 4 * OM_) sOm[idx] = omb[idx];
    }
    __syncthreads();

    const float* vb = value + ((size_t)n * L_) * C_ + g * CG_ + c4;
    const float* so = &sOm[p * OM_ + g * 27];
    float4 acc = make_float4(0.f, 0.f, 0.f, 0.f);
#pragma unroll
    for (int k = 0; k < K_; k++) {
        float offy = so[2 * k];
        float offx = so[2 * k + 1];
        float mk   = so[18 + k];
        float py = (float)(y + k / 3 - 1) + offy;
        float px = (float)(x + k % 3 - 1) + offx;
        float fy = floorf(py), fx = floorf(px);
        float ty = py - fy, tx = px - fx;
        int y0 = (int)fy, x0 = (int)fx;
        int y1 = y0 + 1,  x1 = x0 + 1;
        float vy0 = ((unsigned)y0 < (unsigned)H_) ? 1.f : 0.f;
        float vy1 = ((unsigned)y1 < (unsigned)H_) ? 1.f : 0.f;
        float vx0 = ((unsigned)x0 < (unsigned)W_) ? 1.f : 0.f;
        float vx1 = ((unsigned)x1 < (unsigned)W_) ? 1.f : 0.f;
        int cy0 = min(max(y0, 0), H_ - 1), cy1 = min(max(y1, 0), H_ - 1);
        int cx0 = min(max(x0, 0), W_ - 1), cx1 = min(max(x1, 0), W_ - 1);
        float w00 = mk * (1.f - ty) * (1.f - tx) * vy0 * vx0;
        float w01 = mk * (1.f - ty) * tx         * vy0 * vx1;
        float w10 = mk * ty         * (1.f - tx) * vy1 * vx0;
        float w11 = mk * ty         * tx         * vy1 * vx1;
        float4 v00 = *(const float4*)(vb + (size_t)(cy0 * W_ + cx0) * C_);
        float4 v01 = *(const float4*)(vb + (size_t)(cy0 * W_ + cx1) * C_);
        float4 v10 = *(const float4*)(vb + (size_t)(cy1 * W_ + cx0) * C_);
        float4 v11 = *(const float4*)(vb + (size_t)(cy1 * W_ + cx1) * C_);
        acc.x += w00 * v00.x + w01 * v01.x + w10 * v10.x + w11 * v11.x;
        acc.y += w00 * v00.y + w01 * v01.y + w10 * v10.y + w11 * v11.y;
        acc.z += w00 * v00.z + w01 * v01.z + w10 * v10.z + w11 * v11.z;
        acc.w += w00 * v00.w + w01 * v01.w + w10 * v10.w + w11 * v11.w;
    }
    *(float4*)(interm + ((size_t)n * L_ + l) * C_ + g * CG_ + c4) = acc;
}

// ---------------------------------------------------------------------------
// Kernel 4: final GEMM, A row-major (L_ x C_), output TRANSPOSED: (C_ x L_)
// ---------------------------------------------------------------------------
__global__ __launch_bounds__(256) void gemm_final(const float* __restrict__ A,
                                                  const float* __restrict__ Wm,
                                                  float* __restrict__ Dt) {
    __shared__ float As[16][68];   // [k][m]
    __shared__ float Ws[16][68];   // [k][q]
    const int n = blockIdx.z;
    const int m0 = blockIdx.x * 64;
    const int q0 = blockIdx.y * 64;
    const int tid = threadIdx.x;
    const int tx = tid & 15;   // m-frag
    const int ty = tid >> 4;   // q-frag
    const float* Ab = A + (size_t)n * L_ * C_;
    float acc[4][4] = {{0.f}};   // [m_i][q_j]

    for (int k0 = 0; k0 < C_; k0 += 16) {
        {   // A tile (row-major rows) -> transposed store As[k][m]
            int mi = tid >> 2, k4 = (tid & 3) * 4;
            float4 av = *(const float4*)(Ab + (size_t)(m0 + mi) * C_ + k0 + k4);
            As[k4 + 0][mi] = av.x; As[k4 + 1][mi] = av.y;
            As[k4 + 2][mi] = av.z; As[k4 + 3][mi] = av.w;
        }
        {   // W tile -> transposed store Ws[k][q]
            int qi = tid >> 2, k4 = (tid & 3) * 4;
            float4 wv = *(const float4*)(Wm + (size_t)(q0 + qi) * C_ + k0 + k4);
            Ws[k4 + 0][qi] = wv.x; Ws[k4 + 1][qi] = wv.y;
            Ws[k4 + 2][qi] = wv.z; Ws[k4 + 3][qi] = wv.w;
        }
        __syncthreads();
#pragma unroll
        for (int k = 0; k < 16; k++) {
            float4 a4 = *(const float4*)&As[k][tx * 4];
            float4 w4 = *(const float4*)&Ws[k][ty * 4];
            float am[4] = {a4.x, a4.y, a4.z, a4.w};
            float wq[4] = {w4.x, w4.y, w4.z, w4.w};
#pragma unroll
            for (int i = 0; i < 4; i++)
#pragma unroll
                for (int j = 0; j < 4; j++) acc[i][j] += am[i] * wq[j];
        }
        __syncthreads();
    }

    float* Db = Dt + (size_t)n * C_ * L_;
#pragma unroll
    for (int j = 0; j < 4; j++) {
        int q = q0 + ty * 4 + j;
        float4 v = make_float4(acc[0][j], acc[1][j], acc[2][j], acc[3][j]);
        *(float4*)(Db + (size_t)q * L_ + m0 + tx * 4) = v;
    }
}

// ---------------------------------------------------------------------------
// Launch. Workspace layout (needs 95,420,416 B):
//   [0, 33554432)            value  (N,L,C)  fp32
//   [33554432, 61865984)     om     (N,L,216) fp32
//   [61865984, 95420416)     buf    (N,L,C)  fp32 — om_in, then reused as interm
// ---------------------------------------------------------------------------
extern "C" void kernel_launch(void* const* d_in, const int* in_sizes, int n_in,
                              void* d_out, int out_size, void* d_ws, size_t ws_size,
                              hipStream_t stream) {
    const float* x    = (const float*)d_in[0];
    const float* dw_w = (const float*)d_in[1];
    const float* dw_b = (const float*)d_in[2];
    const float* om_w = (const float*)d_in[3];
    const float* om_b = (const float*)d_in[4];
    const float* vp_w = (const float*)d_in[5];
    const float* vp_b = (const float*)d_in[6];
    const float* op_w = (const float*)d_in[7];
    float* out = (float*)d_out;

    char* ws = (char*)d_ws;
    float* value = (float*)(ws);
    float* om    = (float*)(ws + 33554432);
    float* buf   = (float*)(ws + 61865984);   // om_in then interm

    // 1) depthwise conv -> buf (om_in)
    dw_kernel<<<dim3(H_ / 4, C_, N_), 256, 0, stream>>>(x, dw_w, dw_b, buf);
    // 2) value projection: value = x^T @ vp_w^T + vp_b
    gemm_akm<256><<<dim3(L_ / 64, 4, N_), 256, 0, stream>>>(x, vp_w, vp_b, value);
    // 3) offset/mask projection: om = om_in^T @ om_w^T + om_b
    gemm_akm<216><<<dim3(L_ / 64, 4, N_), 256, 0, stream>>>(buf, om_w, om_b, om);
    // 4) deformable sampling -> buf (interm, overwrites om_in after it's consumed)
    sample_kernel<<<dim3(L_ / 4, N_), 256, 0, stream>>>(value, om, buf);
    // 5) output projection (transposed store -> NCHW out)
    gemm_final<<<dim3(L_ / 64, C_ / 64, N_), 256, 0, stream>>>(buf, op_w, out);
}

// Round 3
// 185.071 us; speedup vs baseline: 2.6362x; 1.8615x over previous
//
#include <hip/hip_runtime.h>
#include <math.h>

// Problem constants
#define N_  8
#define C_  256
#define G_  8
#define CG_ 32
#define K_  9
#define H_  64
#define W_  64
#define L_  (H_*W_)      // 4096
#define OM_ 216          // G*K*3
#define OMP_ 256         // padded om row stride

using frag_ab = __attribute__((ext_vector_type(8))) short;   // 8 bf16
using frag_cd = __attribute__((ext_vector_type(4))) float;   // 4 fp32

__device__ __forceinline__ unsigned short f2bf(float f) {    // RNE fp32->bf16
    unsigned int u = __float_as_uint(f);
    u += 0x7FFFu + ((u >> 16) & 1u);
    return (unsigned short)(u >> 16);
}
__device__ __forceinline__ float bflo(unsigned int u) { return __uint_as_float(u << 16); }
__device__ __forceinline__ float bfhi(unsigned int u) { return __uint_as_float(u & 0xFFFF0000u); }

__device__ __forceinline__ void gld16(const void* g, void* l) {
    __builtin_amdgcn_global_load_lds((const __attribute__((address_space(1))) void*)g,
                                     (__attribute__((address_space(3))) void*)l, 16, 0, 0);
}

// ---------------------------------------------------------------------------
// Weight conversion: vp_w/op_w (256x256), om_w (216x256 -> zero-padded 256x256),
// om_b (216 -> padded 256 fp32). grid 256 x 256 threads.
// ---------------------------------------------------------------------------
__global__ __launch_bounds__(256) void cvt_weights(const float* __restrict__ vp_w,
                                                   const float* __restrict__ om_w,
                                                   const float* __restrict__ om_b,
                                                   const float* __restrict__ op_w,
                                                   unsigned short* __restrict__ vp_wb,
                                                   unsigned short* __restrict__ om_wb,
                                                   float* __restrict__ om_bp,
                                                   unsigned short* __restrict__ op_wb) {
    int idx = blockIdx.x * 256 + threadIdx.x;
    if (idx < C_ * C_) {
        vp_wb[idx] = f2bf(vp_w[idx]);
        op_wb[idx] = f2bf(op_w[idx]);
        om_wb[idx] = (idx < OM_ * C_) ? f2bf(om_w[idx]) : (unsigned short)0;
    }
    if (idx < OMP_) om_bp[idx] = (idx < OM_) ? om_b[idx] : 0.f;
}

// ---------------------------------------------------------------------------
// Fused depthwise 3x3 conv + transpose + bf16 convert: x (n,C,L) fp32 ->
// omb (n,L,C) bf16. grid (C/32, H, N), block 256 = (c 0..31) x (xq 0..7),
// each thread computes 8 consecutive x-positions for one channel.
// LDS slab: 3 rows x 32 ch x (64+2 halo) fp32.
// ---------------------------------------------------------------------------
__global__ __launch_bounds__(256) void dwt_kernel(const float* __restrict__ x,
                                                  const float* __restrict__ w,
                                                  const float* __restrict__ b,
                                                  unsigned short* __restrict__ omb) {
    const int n = blockIdx.z, y = blockIdx.y, c0 = blockIdx.x * 32;
    const int tid = threadIdx.x;
    __shared__ float xs[3][32][66];
    if (tid < 192) {    // zero the x = -1 / 64 halo columns
        int r = tid / 64, c = (tid / 2) % 32, e = tid & 1;
        xs[r][c][e * 65] = 0.f;
    }
    const float* xb = x + ((size_t)n * C_ + c0) * L_;
    for (int i = tid; i < 3 * 32 * 16; i += 256) {   // 3 rows x 32 ch x 16 float4
        int r = i >> 9;
        int rem = i & 511;
        int c = rem >> 4;
        int x4 = (rem & 15) * 4;
        int yy = y + r - 1;
        float4 v = make_float4(0.f, 0.f, 0.f, 0.f);
        if ((unsigned)yy < (unsigned)H_) v = *(const float4*)(xb + (size_t)c * L_ + yy * W_ + x4);
        xs[r][c][1 + x4] = v.x; xs[r][c][2 + x4] = v.y;
        xs[r][c][3 + x4] = v.z; xs[r][c][4 + x4] = v.w;
    }
    __syncthreads();

    const int c = tid & 31, x0 = (tid >> 5) * 8;
    float wv[9];
#pragma unroll
    for (int i = 0; i < 9; i++) wv[i] = w[(c0 + c) * 9 + i];
    const float bias = b[c0 + c];
    float o[8];
#pragma unroll
    for (int j = 0; j < 8; j++) o[j] = bias;
#pragma unroll
    for (int r = 0; r < 3; r++) {
        float v[10];
#pragma unroll
        for (int d = 0; d < 10; d++) v[d] = xs[r][c][x0 + d];
#pragma unroll
        for (int j = 0; j < 8; j++)
            o[j] += wv[r * 3] * v[j] + wv[r * 3 + 1] * v[j + 1] + wv[r * 3 + 2] * v[j + 2];
    }
#pragma unroll
    for (int j = 0; j < 8; j++)
        omb[((size_t)n * L_ + y * W_ + x0 + j) * C_ + c0 + c] = f2bf(o[j]);
}

// ---------------------------------------------------------------------------
// Transpose + convert: x (n,C,L) fp32 -> xb (n,L,C) bf16.
// grid (L/64, C/32, N), block 256. LDS tile 32(c) x 64(l), padded.
// ---------------------------------------------------------------------------
__global__ __launch_bounds__(256) void xcvt_kernel(const float* __restrict__ x,
                                                   unsigned short* __restrict__ xb) {
    const int n = blockIdx.z, c0 = blockIdx.y * 32, l0 = blockIdx.x * 64;
    const int tid = threadIdx.x;
    __shared__ float t[32][65];
    {
        int c = tid >> 3, l8 = (tid & 7) * 8;
        const float* src = x + ((size_t)n * C_ + c0 + c) * L_ + l0 + l8;
        float4 a = *(const float4*)src;
        float4 d = *(const float4*)(src + 4);
        t[c][l8 + 0] = a.x; t[c][l8 + 1] = a.y; t[c][l8 + 2] = a.z; t[c][l8 + 3] = a.w;
        t[c][l8 + 4] = d.x; t[c][l8 + 5] = d.y; t[c][l8 + 6] = d.z; t[c][l8 + 7] = d.w;
    }
    __syncthreads();
    {
        int l = tid >> 2, cq = (tid & 3) * 8;
        uint4 pk;
        unsigned short* pp = (unsigned short*)&pk;
#pragma unroll
        for (int i = 0; i < 8; i++) pp[i] = f2bf(t[cq + i][l]);
        *(uint4*)(xb + ((size_t)n * L_ + l0 + l) * C_ + c0 + cq) = pk;
    }
}

// ---------------------------------------------------------------------------
// bf16 MFMA GEMM (m97 structure): C[i][j] = sum_k A[i][k]*B[j][k] (+bias[j])
// A: (M x 256) bf16 row-major; B: (256-row x 256) bf16 row-major (per batch
// via bbatch); D: fp32 or bf16, row stride drow, batch stride dbatch.
// Block 256 (4 waves), tile 128x128, BK=32, mfma 16x16x32, 4x4 tiles/wave.
// ---------------------------------------------------------------------------
template <bool BF16_OUT, bool BIAS>
__global__ __launch_bounds__(256) void gemm_bf16(const unsigned short* __restrict__ A,
                                                 const unsigned short* __restrict__ B,
                                                 const float* __restrict__ bias,
                                                 void* __restrict__ Dv,
                                                 int drow, long bbatch, long dbatch) {
    __shared__ unsigned short As[128 * 32];
    __shared__ unsigned short Bs[128 * 32];
    const int tid = threadIdx.x;
    const long i0 = (long)blockIdx.x * 128;
    const long j0 = (long)blockIdx.y * 128;
    const unsigned short* Ab = A + i0 * C_;
    const unsigned short* Bb = B + bbatch * blockIdx.z + j0 * C_;
    const int wave = tid >> 6, lane = tid & 63;
    const int iw = (wave & 1) * 64, jw = (wave >> 1) * 64;
    const int lm = lane & 15, kq = lane >> 4;
    const int srow = tid >> 2, scol = (tid & 3) * 8;

    frag_cd acc[4][4];
#pragma unroll
    for (int a = 0; a < 4; a++)
#pragma unroll
        for (int c = 0; c < 4; c++) acc[a][c] = (frag_cd){0.f, 0.f, 0.f, 0.f};

    for (int k0 = 0; k0 < C_; k0 += 32) {
        const unsigned short* ga0 = Ab + (long)srow * C_ + k0 + scol;
        const unsigned short* gb0 = Bb + (long)srow * C_ + k0 + scol;
        gld16(ga0,            As + tid * 8);
        gld16(ga0 + 64 * C_,  As + 2048 + tid * 8);
        gld16(gb0,            Bs + tid * 8);
        gld16(gb0 + 64 * C_,  Bs + 2048 + tid * 8);
        __syncthreads();
        frag_ab af[4], bfr[4];
#pragma unroll
        for (int mi = 0; mi < 4; mi++)
            af[mi] = *(const frag_ab*)&As[(iw + mi * 16 + lm) * 32 + kq * 8];
#pragma unroll
        for (int ni = 0; ni < 4; ni++)
            bfr[ni] = *(const frag_ab*)&Bs[(jw + ni * 16 + lm) * 32 + kq * 8];
#pragma unroll
        for (int mi = 0; mi < 4; mi++)
#pragma unroll
            for (int ni = 0; ni < 4; ni++)
                acc[mi][ni] = __builtin_amdgcn_mfma_f32_16x16x32_bf16(af[mi], bfr[ni], acc[mi][ni], 0, 0, 0);
        __syncthreads();
    }

    float bv[4];
#pragma unroll
    for (int ni = 0; ni < 4; ni++)
        bv[ni] = BIAS ? bias[(int)(j0 + jw + ni * 16 + lm)] : 0.f;

    const long ibase = i0 + iw + kq * 4;
    const long jbase = j0 + jw + lm;
    const long dz = dbatch * blockIdx.z;
#pragma unroll
    for (int mi = 0; mi < 4; mi++) {
#pragma unroll
        for (int ni = 0; ni < 4; ni++) {
            long j = jbase + ni * 16;
#pragma unroll
            for (int r = 0; r < 4; r++) {
                long i = ibase + mi * 16 + r;
                float v = acc[mi][ni][r] + bv[ni];
                if (BF16_OUT)
                    ((unsigned short*)Dv)[dz + i * drow + j] = f2bf(v);
                else
                    ((float*)Dv)[dz + i * drow + j] = v;
            }
        }
    }
}

// ---------------------------------------------------------------------------
// Deformable bilinear sampling: value bf16 (n,L,C), om fp32 (n,L,256-padded),
// out interm bf16 (n,L,C). grid (L/8, N), block 256: 8 pixels x (8 g x 4 thr),
// each thread covers 8 channels via 16B uint4 gathers.
// ---------------------------------------------------------------------------
__global__ __launch_bounds__(256) void sample_kernel(const unsigned short* __restrict__ value,
                                                     const float* __restrict__ om,
                                                     unsigned short* __restrict__ interm) {
    const int n = blockIdx.y;
    const int l0 = blockIdx.x * 8;
    const int tid = threadIdx.x;
    const int p = tid >> 5;
    const int l = l0 + p;
    const int y = l >> 6, xp = l & 63;
    const int g = (tid >> 2) & 7;
    const int c8 = (tid & 3) * 8;

    __shared__ float sOm[8 * OM_];
    const float* omsrc = om + ((size_t)n * L_ + l0) * OMP_;
    for (int i = tid; i < 8 * OM_; i += 256) {
        int pp = i / OM_;
        int j = i - pp * OM_;
        sOm[i] = omsrc[pp * OMP_ + j];
    }
    __syncthreads();

    const unsigned short* vb = value + (size_t)n * L_ * C_ + g * CG_ + c8;
    const float* so = &sOm[p * OM_ + g * 27];
    float acc[8] = {0.f, 0.f, 0.f, 0.f, 0.f, 0.f, 0.f, 0.f};
#pragma unroll
    for (int k = 0; k < K_; k++) {
        float offy = so[2 * k], offx = so[2 * k + 1], mk = so[18 + k];
        float py = (float)(y + k / 3 - 1) + offy;
        float px = (float)(xp + k % 3 - 1) + offx;
        float fy = floorf(py), fx = floorf(px);
        float ty = py - fy, tx = px - fx;
        int y0 = (int)fy, x0 = (int)fx;
        int y1 = y0 + 1, x1 = x0 + 1;
        float vy0 = ((unsigned)y0 < (unsigned)H_) ? 1.f : 0.f;
        float vy1 = ((unsigned)y1 < (unsigned)H_) ? 1.f : 0.f;
        float vx0 = ((unsigned)x0 < (unsigned)W_) ? 1.f : 0.f;
        float vx1 = ((unsigned)x1 < (unsigned)W_) ? 1.f : 0.f;
        int cy0 = min(max(y0, 0), H_ - 1), cy1 = min(max(y1, 0), H_ - 1);
        int cx0 = min(max(x0, 0), W_ - 1), cx1 = min(max(x1, 0), W_ - 1);
        float w00 = mk * (1.f - ty) * (1.f - tx) * vy0 * vx0;
        float w01 = mk * (1.f - ty) * tx * vy0 * vx1;
        float w10 = mk * ty * (1.f - tx) * vy1 * vx0;
        float w11 = mk * ty * tx * vy1 * vx1;
        const uint4 v00 = *(const uint4*)(vb + (size_t)(cy0 * W_ + cx0) * C_);
        const uint4 v01 = *(const uint4*)(vb + (size_t)(cy0 * W_ + cx1) * C_);
        const uint4 v10 = *(const uint4*)(vb + (size_t)(cy1 * W_ + cx0) * C_);
        const uint4 v11 = *(const uint4*)(vb + (size_t)(cy1 * W_ + cx1) * C_);
#define ACC8(V, WW) { \
        acc[0] += WW * bflo(V.x); acc[1] += WW * bfhi(V.x); \
        acc[2] += WW * bflo(V.y); acc[3] += WW * bfhi(V.y); \
        acc[4] += WW * bflo(V.z); acc[5] += WW * bfhi(V.z); \
        acc[6] += WW * bflo(V.w); acc[7] += WW * bfhi(V.w); }
        ACC8(v00, w00) ACC8(v01, w01) ACC8(v10, w10) ACC8(v11, w11)
#undef ACC8
    }
    uint4 pk;
    unsigned short* pp2 = (unsigned short*)&pk;
#pragma unroll
    for (int i = 0; i < 8; i++) pp2[i] = f2bf(acc[i]);
    *(uint4*)(interm + ((size_t)n * L_ + l) * C_ + g * CG_ + c8) = pk;
}

// ---------------------------------------------------------------------------
// Workspace layout (84,280,320 B total):
//   [0,        16777216)  xb (n,L,C) bf16  -> reused as intermb after GEMM1
//   [16777216, 33554432)  omb (n,L,C) bf16
//   [33554432, 50331648)  valueb (n,L,C) bf16
//   [50331648, 83886080)  omf (n,L,256) fp32
//   [83886080, ...)       vp_wb, om_wb, op_wb bf16 (128KB each), om_bp fp32
// ---------------------------------------------------------------------------
extern "C" void kernel_launch(void* const* d_in, const int* in_sizes, int n_in,
                              void* d_out, int out_size, void* d_ws, size_t ws_size,
                              hipStream_t stream) {
    const float* x    = (const float*)d_in[0];
    const float* dw_w = (const float*)d_in[1];
    const float* dw_b = (const float*)d_in[2];
    const float* om_w = (const float*)d_in[3];
    const float* om_b = (const float*)d_in[4];
    const float* vp_w = (const float*)d_in[5];
    const float* vp_b = (const float*)d_in[6];
    const float* op_w = (const float*)d_in[7];
    float* out = (float*)d_out;

    char* ws = (char*)d_ws;
    unsigned short* xb      = (unsigned short*)(ws);                 // also intermb
    unsigned short* omb     = (unsigned short*)(ws + 16777216);
    unsigned short* valueb  = (unsigned short*)(ws + 33554432);
    float*          omf     = (float*)(ws + 50331648);
    unsigned short* vp_wb   = (unsigned short*)(ws + 83886080);
    unsigned short* om_wb   = (unsigned short*)(ws + 84017152);
    unsigned short* op_wb   = (unsigned short*)(ws + 84148224);
    float*          om_bp   = (float*)(ws + 84279296);
    unsigned short* intermb = xb;

    cvt_weights<<<dim3(256), 256, 0, stream>>>(vp_w, om_w, om_b, op_w,
                                               vp_wb, om_wb, om_bp, op_wb);
    dwt_kernel<<<dim3(C_ / 32, H_, N_), 256, 0, stream>>>(x, dw_w, dw_b, omb);
    xcvt_kernel<<<dim3(L_ / 64, C_ / 32, N_), 256, 0, stream>>>(x, xb);
    // value = xb @ vp_w^T + vp_b  (bf16 out, row stride 256)
    gemm_bf16<true, true><<<dim3(256, 2, 1), 256, 0, stream>>>(
        xb, vp_wb, vp_b, valueb, C_, 0, 0);
    // om = omb @ om_w^T + om_b  (fp32 out, padded stride 256)
    gemm_bf16<false, true><<<dim3(256, 2, 1), 256, 0, stream>>>(
        omb, om_wb, om_bp, omf, OMP_, 0, 0);
    // sampling -> intermb (reuses xb buffer; xb fully consumed by GEMM1)
    sample_kernel<<<dim3(L_ / 8, N_), 256, 0, stream>>>(valueb, omf, intermb);
    // out[n][q][l] = op_w @ intermb[n]^T  (fp32, directly NCHW)
    gemm_bf16<false, false><<<dim3(2, 32, N_), 256, 0, stream>>>(
        op_wb, intermb, nullptr, out, L_, (long)L_ * C_, (long)C_ * L_);
}

// Round 4
// 176.450 us; speedup vs baseline: 2.7650x; 1.0489x over previous
//
#include <hip/hip_runtime.h>
#include <math.h>

// Problem constants
#define N_  8
#define C_  256
#define G_  8
#define CG_ 32
#define K_  9
#define H_  64
#define W_  64
#define L_  (H_*W_)      // 4096
#define OM_ 216          // G*K*3
#define OMP_ 256         // padded om row stride

using frag_ab = __attribute__((ext_vector_type(8))) short;   // 8 bf16
using frag_cd = __attribute__((ext_vector_type(4))) float;   // 4 fp32

__device__ __forceinline__ unsigned short f2bf(float f) {    // RNE fp32->bf16
    unsigned int u = __float_as_uint(f);
    u += 0x7FFFu + ((u >> 16) & 1u);
    return (unsigned short)(u >> 16);
}
__device__ __forceinline__ float bflo(unsigned int u) { return __uint_as_float(u << 16); }
__device__ __forceinline__ float bfhi(unsigned int u) { return __uint_as_float(u & 0xFFFF0000u); }

__device__ __forceinline__ void gld16(const void* g, void* l) {
    __builtin_amdgcn_global_load_lds((const __attribute__((address_space(1))) void*)g,
                                     (__attribute__((address_space(3))) void*)l, 16, 0, 0);
}

// ---------------------------------------------------------------------------
// Weight conversion: vp_w/op_w (256x256), om_w (216x256 -> zero-padded 256x256),
// om_b (216 -> padded 256 fp32). grid 256 x 256 threads.
// ---------------------------------------------------------------------------
__global__ __launch_bounds__(256) void cvt_weights(const float* __restrict__ vp_w,
                                                   const float* __restrict__ om_w,
                                                   const float* __restrict__ om_b,
                                                   const float* __restrict__ op_w,
                                                   unsigned short* __restrict__ vp_wb,
                                                   unsigned short* __restrict__ om_wb,
                                                   float* __restrict__ om_bp,
                                                   unsigned short* __restrict__ op_wb) {
    int idx = blockIdx.x * 256 + threadIdx.x;
    if (idx < C_ * C_) {
        vp_wb[idx] = f2bf(vp_w[idx]);
        op_wb[idx] = f2bf(op_w[idx]);
        om_wb[idx] = (idx < OM_ * C_) ? f2bf(om_w[idx]) : (unsigned short)0;
    }
    if (idx < OMP_) om_bp[idx] = (idx < OM_) ? om_b[idx] : 0.f;
}

// ---------------------------------------------------------------------------
// Fused prep: depthwise 3x3 conv + transpose + bf16 convert of BOTH the conv
// output (omb) and the raw x row (xb), single pass over x.
// grid (C/32, H, N), block 256 = (c 0..31) x (xq 0..7).
// LDS: 3-row slab (fp32, halo-padded) + two 64x40 ushort transpose tiles.
// ---------------------------------------------------------------------------
__global__ __launch_bounds__(256) void prep_kernel(const float* __restrict__ x,
                                                   const float* __restrict__ w,
                                                   const float* __restrict__ b,
                                                   unsigned short* __restrict__ xb,
                                                   unsigned short* __restrict__ omb) {
    const int n = blockIdx.z, y = blockIdx.y, c0 = blockIdx.x * 32;
    const int tid = threadIdx.x;
    __shared__ float xs[3][32][66];
    __shared__ __align__(16) unsigned short os[2][64][40];  // [0]=x bf16, [1]=conv
    if (tid < 192) {    // zero the x = -1 / 64 halo columns
        int r = tid / 64, c = (tid / 2) % 32, e = tid & 1;
        xs[r][c][e * 65] = 0.f;
    }
    const float* xbase = x + ((size_t)n * C_ + c0) * L_;
    for (int i = tid; i < 3 * 32 * 16; i += 256) {   // 3 rows x 32 ch x 16 float4
        int r = i >> 9, rem = i & 511, c = rem >> 4, x4 = (rem & 15) * 4;
        int yy = y + r - 1;
        float4 v = make_float4(0.f, 0.f, 0.f, 0.f);
        if ((unsigned)yy < (unsigned)H_) v = *(const float4*)(xbase + (size_t)c * L_ + yy * W_ + x4);
        xs[r][c][1 + x4] = v.x; xs[r][c][2 + x4] = v.y;
        xs[r][c][3 + x4] = v.z; xs[r][c][4 + x4] = v.w;
    }
    __syncthreads();

    const int c = tid & 31, x0 = (tid >> 5) * 8;
    float wv[9];
#pragma unroll
    for (int i = 0; i < 9; i++) wv[i] = w[(c0 + c) * 9 + i];
    const float bias = b[c0 + c];
    float o[8];
#pragma unroll
    for (int j = 0; j < 8; j++) o[j] = bias;
#pragma unroll
    for (int r = 0; r < 3; r++) {
        float v[10];
#pragma unroll
        for (int d = 0; d < 10; d++) v[d] = xs[r][c][x0 + d];
#pragma unroll
        for (int j = 0; j < 8; j++)
            o[j] += wv[r * 3] * v[j] + wv[r * 3 + 1] * v[j + 1] + wv[r * 3 + 2] * v[j + 2];
    }
#pragma unroll
    for (int j = 0; j < 8; j++) {
        os[0][x0 + j][c] = f2bf(xs[1][c][1 + x0 + j]);
        os[1][x0 + j][c] = f2bf(o[j]);
    }
    __syncthreads();

    const int l = tid >> 2, c8 = (tid & 3) * 8;
    uint4 va = *(const uint4*)&os[0][l][c8];
    uint4 vc = *(const uint4*)&os[1][l][c8];
    size_t dst = ((size_t)n * L_ + y * W_ + l) * C_ + c0 + c8;
    *(uint4*)(xb + dst) = va;
    *(uint4*)(omb + dst) = vc;
}

// ---------------------------------------------------------------------------
// bf16 MFMA GEMM (m97 structure): C[i][j] = sum_k A[i][k]*B[j][k] (+bias[j])
// Block 256 (4 waves), tile 128x128, BK=32, mfma 16x16x32, 4x4 tiles/wave.
// ---------------------------------------------------------------------------
template <bool BF16_OUT, bool BIAS>
__global__ __launch_bounds__(256) void gemm_bf16(const unsigned short* __restrict__ A,
                                                 const unsigned short* __restrict__ B,
                                                 const float* __restrict__ bias,
                                                 void* __restrict__ Dv,
                                                 int drow, long bbatch, long dbatch) {
    __shared__ unsigned short As[128 * 32];
    __shared__ unsigned short Bs[128 * 32];
    const int tid = threadIdx.x;
    const long i0 = (long)blockIdx.x * 128;
    const long j0 = (long)blockIdx.y * 128;
    const unsigned short* Ab = A + i0 * C_;
    const unsigned short* Bb = B + bbatch * blockIdx.z + j0 * C_;
    const int wave = tid >> 6, lane = tid & 63;
    const int iw = (wave & 1) * 64, jw = (wave >> 1) * 64;
    const int lm = lane & 15, kq = lane >> 4;
    const int srow = tid >> 2, scol = (tid & 3) * 8;

    frag_cd acc[4][4];
#pragma unroll
    for (int a = 0; a < 4; a++)
#pragma unroll
        for (int c = 0; c < 4; c++) acc[a][c] = (frag_cd){0.f, 0.f, 0.f, 0.f};

    for (int k0 = 0; k0 < C_; k0 += 32) {
        const unsigned short* ga0 = Ab + (long)srow * C_ + k0 + scol;
        const unsigned short* gb0 = Bb + (long)srow * C_ + k0 + scol;
        gld16(ga0,            As + tid * 8);
        gld16(ga0 + 64 * C_,  As + 2048 + tid * 8);
        gld16(gb0,            Bs + tid * 8);
        gld16(gb0 + 64 * C_,  Bs + 2048 + tid * 8);
        __syncthreads();
        frag_ab af[4], bfr[4];
#pragma unroll
        for (int mi = 0; mi < 4; mi++)
            af[mi] = *(const frag_ab*)&As[(iw + mi * 16 + lm) * 32 + kq * 8];
#pragma unroll
        for (int ni = 0; ni < 4; ni++)
            bfr[ni] = *(const frag_ab*)&Bs[(jw + ni * 16 + lm) * 32 + kq * 8];
#pragma unroll
        for (int mi = 0; mi < 4; mi++)
#pragma unroll
            for (int ni = 0; ni < 4; ni++)
                acc[mi][ni] = __builtin_amdgcn_mfma_f32_16x16x32_bf16(af[mi], bfr[ni], acc[mi][ni], 0, 0, 0);
        __syncthreads();
    }

    float bv[4];
#pragma unroll
    for (int ni = 0; ni < 4; ni++)
        bv[ni] = BIAS ? bias[(int)(j0 + jw + ni * 16 + lm)] : 0.f;

    const long ibase = i0 + iw + kq * 4;
    const long jbase = j0 + jw + lm;
    const long dz = dbatch * blockIdx.z;
#pragma unroll
    for (int mi = 0; mi < 4; mi++) {
#pragma unroll
        for (int ni = 0; ni < 4; ni++) {
            long j = jbase + ni * 16;
#pragma unroll
            for (int r = 0; r < 4; r++) {
                long i = ibase + mi * 16 + r;
                float v = acc[mi][ni][r] + bv[ni];
                if (BF16_OUT)
                    ((unsigned short*)Dv)[dz + i * drow + j] = f2bf(v);
                else
                    ((float*)Dv)[dz + i * drow + j] = v;
            }
        }
    }
}

// ---------------------------------------------------------------------------
// Deformable bilinear sampling, two-phase:
//   phase 1: 576 items (64 (pixel,g) pairs x 9 taps) -> mask-premultiplied
//            bilinear weights (float4) + clamped byte offsets (uint4) in LDS.
//   phase 2: thread = (pair, c8): 8 channels via uint4 bf16 gathers; per tap
//            just 2 ds_read_b128 + 4 addr-adds + unpack/FMA.
// grid (L/8, N), block 256.
// ---------------------------------------------------------------------------
__global__ __launch_bounds__(256) void sample_kernel(const unsigned short* __restrict__ value,
                                                     const float* __restrict__ om,
                                                     unsigned short* __restrict__ interm) {
    const int n = blockIdx.y;
    const int l0 = blockIdx.x * 8;
    const int tid = threadIdx.x;

    __shared__ float sOm[8 * OM_];        // 6912 B
    __shared__ float4 wgt[64][9];         // 9216 B
    __shared__ uint4  soff[64][9];        // 9216 B

    const float* omsrc = om + ((size_t)n * L_ + l0) * OMP_;
    for (int i = tid; i < 8 * OM_; i += 256) {
        int pp = i / OM_;
        sOm[i] = omsrc[pp * OMP_ + (i - pp * OM_)];
    }
    __syncthreads();

    for (int it = tid; it < 576; it += 256) {
        int pair = it / 9, k = it - pair * 9;
        int p = pair >> 3, g = pair & 7;
        int l = l0 + p, y = l >> 6, xp2 = l & 63;
        const float* so = &sOm[p * OM_ + g * 27];
        float offy = so[2 * k], offx = so[2 * k + 1], mk = so[18 + k];
        float py = (float)(y + k / 3 - 1) + offy;
        float px = (float)(xp2 + k % 3 - 1) + offx;
        float fy = floorf(py), fx = floorf(px);
        float ty = py - fy, tx = px - fx;
        int y0 = (int)fy, x0i = (int)fx;
        int y1 = y0 + 1, x1 = x0i + 1;
        float vy0 = ((unsigned)y0 < (unsigned)H_) ? 1.f : 0.f;
        float vy1 = ((unsigned)y1 < (unsigned)H_) ? 1.f : 0.f;
        float vx0 = ((unsigned)x0i < (unsigned)W_) ? 1.f : 0.f;
        float vx1 = ((unsigned)x1 < (unsigned)W_) ? 1.f : 0.f;
        int cy0 = min(max(y0, 0), H_ - 1), cy1 = min(max(y1, 0), H_ - 1);
        int cx0 = min(max(x0i, 0), W_ - 1), cx1 = min(max(x1, 0), W_ - 1);
        wgt[pair][k] = make_float4(mk * (1.f - ty) * (1.f - tx) * vy0 * vx0,
                                   mk * (1.f - ty) * tx         * vy0 * vx1,
                                   mk * ty         * (1.f - tx) * vy1 * vx0,
                                   mk * ty         * tx         * vy1 * vx1);
        soff[pair][k] = make_uint4((unsigned)((cy0 * W_ + cx0) << 9),
                                   (unsigned)((cy0 * W_ + cx1) << 9),
                                   (unsigned)((cy1 * W_ + cx0) << 9),
                                   (unsigned)((cy1 * W_ + cx1) << 9));
    }
    __syncthreads();

    const int pair = tid >> 2, p = pair >> 3, g = pair & 7, c8 = (tid & 3) * 8;
    const char* vb = (const char*)(value + (size_t)n * L_ * C_ + g * CG_ + c8);
    float acc[8] = {0.f, 0.f, 0.f, 0.f, 0.f, 0.f, 0.f, 0.f};
#pragma unroll
    for (int k = 0; k < K_; k++) {
        float4 wk = wgt[pair][k];
        uint4  ok = soff[pair][k];
        const uint4 v00 = *(const uint4*)(vb + ok.x);
        const uint4 v01 = *(const uint4*)(vb + ok.y);
        const uint4 v10 = *(const uint4*)(vb + ok.z);
        const uint4 v11 = *(const uint4*)(vb + ok.w);
#define ACC8(V, WW) { \
        acc[0] += WW * bflo(V.x); acc[1] += WW * bfhi(V.x); \
        acc[2] += WW * bflo(V.y); acc[3] += WW * bfhi(V.y); \
        acc[4] += WW * bflo(V.z); acc[5] += WW * bfhi(V.z); \
        acc[6] += WW * bflo(V.w); acc[7] += WW * bfhi(V.w); }
        ACC8(v00, wk.x) ACC8(v01, wk.y) ACC8(v10, wk.z) ACC8(v11, wk.w)
#undef ACC8
    }
    uint4 pk;
    unsigned short* pp2 = (unsigned short*)&pk;
#pragma unroll
    for (int i = 0; i < 8; i++) pp2[i] = f2bf(acc[i]);
    *(uint4*)(interm + ((size_t)n * L_ + l0 + p) * C_ + g * CG_ + c8) = pk;
}

// ---------------------------------------------------------------------------
// Workspace layout (84,280,320 B total):
//   [0,        16777216)  xb (n,L,C) bf16  -> reused as intermb after GEMM1
//   [16777216, 33554432)  omb (n,L,C) bf16
//   [33554432, 50331648)  valueb (n,L,C) bf16
//   [50331648, 83886080)  omf (n,L,256) fp32
//   [83886080, ...)       vp_wb, om_wb, op_wb bf16 (128KB each), om_bp fp32
// ---------------------------------------------------------------------------
extern "C" void kernel_launch(void* const* d_in, const int* in_sizes, int n_in,
                              void* d_out, int out_size, void* d_ws, size_t ws_size,
                              hipStream_t stream) {
    const float* x    = (const float*)d_in[0];
    const float* dw_w = (const float*)d_in[1];
    const float* dw_b = (const float*)d_in[2];
    const float* om_w = (const float*)d_in[3];
    const float* om_b = (const float*)d_in[4];
    const float* vp_w = (const float*)d_in[5];
    const float* vp_b = (const float*)d_in[6];
    const float* op_w = (const float*)d_in[7];
    float* out = (float*)d_out;

    char* ws = (char*)d_ws;
    unsigned short* xb      = (unsigned short*)(ws);                 // also intermb
    unsigned short* omb     = (unsigned short*)(ws + 16777216);
    unsigned short* valueb  = (unsigned short*)(ws + 33554432);
    float*          omf     = (float*)(ws + 50331648);
    unsigned short* vp_wb   = (unsigned short*)(ws + 83886080);
    unsigned short* om_wb   = (unsigned short*)(ws + 84017152);
    unsigned short* op_wb   = (unsigned short*)(ws + 84148224);
    float*          om_bp   = (float*)(ws + 84279296);
    unsigned short* intermb = xb;

    cvt_weights<<<dim3(256), 256, 0, stream>>>(vp_w, om_w, om_b, op_w,
                                               vp_wb, om_wb, om_bp, op_wb);
    // fused depthwise conv + x transpose (single pass over x)
    prep_kernel<<<dim3(C_ / 32, H_, N_), 256, 0, stream>>>(x, dw_w, dw_b, xb, omb);
    // value = xb @ vp_w^T + vp_b  (bf16 out, row stride 256)
    gemm_bf16<true, true><<<dim3(256, 2, 1), 256, 0, stream>>>(
        xb, vp_wb, vp_b, valueb, C_, 0, 0);
    // om = omb @ om_w^T + om_b  (fp32 out, padded stride 256)
    gemm_bf16<false, true><<<dim3(256, 2, 1), 256, 0, stream>>>(
        omb, om_wb, om_bp, omf, OMP_, 0, 0);
    // sampling -> intermb (reuses xb buffer; xb fully consumed by GEMM1)
    sample_kernel<<<dim3(L_ / 8, N_), 256, 0, stream>>>(valueb, omf, intermb);
    // out[n][q][l] = op_w @ intermb[n]^T  (fp32, directly NCHW)
    gemm_bf16<false, false><<<dim3(2, 32, N_), 256, 0, stream>>>(
        op_wb, intermb, nullptr, out, L_, (long)L_ * C_, (long)C_ * L_);
}